// Round 10
// baseline (74.062 us; speedup 1.0000x reference)
//
#include <hip/hip_runtime.h>
#include <hip/hip_bf16.h>
#include <stdint.h>

// GPTQ 4-bit fused dequant + GEMM.  x[128,4096]f32 @ W[4096,11008] -> out[128,11008]f32
// W[k][n] = scales[k/128][n] * nibble(qweight[k/8][n], k%8) - zeros[k/128][n]
//
// R10: bf16-mantissa dequant: bf16(0x4300|q) = 128+q EXACT -> dequant is pure
//      bit-ops. Per group g (128 k = 2 chunks): accg = sum x*(128+q) via MFMA;
//      acc += s_g*accg at group boundary; epilogue subtracts
//      sum_g (128*s_g+z_g)*rsum_g[m]  (rsum = per-group sums of bf16-rounded x,
//      computed in cvt via 16-lane shfl reduce). WM=64 (R8 geometry: 2 MFMAs
//      per dequant), SPLIT=4, 688 blocks, A-prefetch 1-deep, q-prefetch 3-deep.

#define IN_F   4096
#define OUT_F  11008
#define BATCH  128
#define SPLIT  4
#define KSLICE (IN_F / SPLIT)   // 1024
#define KSC    (KSLICE / 64)    // 16 chunks of 64 k
#define NCHG   (IN_F / 64)      // 64 global chunks
#define NBN    86               // n-blocks (128 cols each)
#define NBLK   (NBN * 2 * SPLIT)// 688
#define MN     (BATCH * OUT_F)  // 1409024
#define NGRP   (IN_F / 128)     // 32 groups

typedef __attribute__((ext_vector_type(8)))  short short8;
typedef __attribute__((ext_vector_type(16))) float f32x16;

static __device__ __forceinline__ unsigned int f2bf_pack(float lo, float hi) {
  unsigned int a = __float_as_uint(lo);
  unsigned int b = __float_as_uint(hi);
  a += 0x7FFFu + ((a >> 16) & 1u);
  b += 0x7FFFu + ((b >> 16) & 1u);
  return (a >> 16) | (b & 0xFFFF0000u);
}

static __device__ __forceinline__ float bf16_round_f32(float v) {
  unsigned int u = __float_as_uint(v);
  u += 0x7FFFu + ((u >> 16) & 1u);
  return __uint_as_float(u & 0xFFFF0000u);
}

// x[128][4096] f32 -> xs frag-major bf16 (16B unit = ((mt*64+cg)*4+ks)*64+lane,
// lane = hi*32+lo32, holding x[mt*32+lo32][cg*64+ks*16+hi*8 + 0..7])
// + rsum[128][32]: per-(row, group) sum of the bf16-ROUNDED x values.
__global__ __launch_bounds__(256) void cvt_swz(const float* __restrict__ x,
                                               uint4* __restrict__ xs,
                                               float* __restrict__ rsum) {
  int t  = blockIdx.x * 256 + threadIdx.x;   // 65536 threads
  int m  = t >> 9;                           // 0..127
  int k  = (t & 511) * 8;                    // 0..4088, step 8
  float4 u0 = *(const float4*)(x + (size_t)m * IN_F + k);
  float4 u1 = *(const float4*)(x + (size_t)m * IN_F + k + 4);
  uint4 o;
  o.x = f2bf_pack(u0.x, u0.y);
  o.y = f2bf_pack(u0.z, u0.w);
  o.z = f2bf_pack(u1.x, u1.y);
  o.w = f2bf_pack(u1.z, u1.w);
  int mt = m >> 5, lo32 = m & 31;
  int cg = k >> 6, ks = (k >> 4) & 3, hi = (k >> 3) & 1;
  size_t idx = (size_t)(((mt * NCHG + cg) * 4 + ks) << 6) + hi * 32 + lo32;
  xs[idx] = o;

  // group-sum of rounded values; 16 consecutive threads cover one (m, group)
  float s8 = bf16_round_f32(u0.x) + bf16_round_f32(u0.y) +
             bf16_round_f32(u0.z) + bf16_round_f32(u0.w) +
             bf16_round_f32(u1.x) + bf16_round_f32(u1.y) +
             bf16_round_f32(u1.z) + bf16_round_f32(u1.w);
  s8 += __shfl_xor(s8, 1, 16);
  s8 += __shfl_xor(s8, 2, 16);
  s8 += __shfl_xor(s8, 4, 16);
  s8 += __shfl_xor(s8, 8, 16);
  if ((t & 15) == 0) {
    int g = (t & 511) >> 4;                  // 0..31
    rsum[m * NGRP + g] = s8;
  }
}

__global__ __launch_bounds__(256) void zero_out(float* __restrict__ out) {
  int base = (blockIdx.x * 256 + threadIdx.x) * 16;   // 344 blocks
  float4 z = {0.f, 0.f, 0.f, 0.f};
#pragma unroll
  for (int j = 0; j < 4; ++j) *(float4*)(out + base + j * 4) = z;
}

__global__ __launch_bounds__(256) void reduce_kernel(const float* __restrict__ part,
                                                     float* __restrict__ out) {
  int base = (blockIdx.x * 256 + threadIdx.x) * 8;    // 688 blocks
  float4 s0 = {0.f, 0.f, 0.f, 0.f}, s1 = s0;
#pragma unroll
  for (int s = 0; s < SPLIT; ++s) {
    const float* p = part + (size_t)s * MN + base;
    float4 a = *(const float4*)(p);
    float4 b = *(const float4*)(p + 4);
    s0.x += a.x; s0.y += a.y; s0.z += a.z; s0.w += a.w;
    s1.x += b.x; s1.y += b.y; s1.z += b.z; s1.w += b.w;
  }
  *(float4*)(out + base)     = s0;
  *(float4*)(out + base + 4) = s1;
}

// dequant one packed int32 into bf16 (128 + q) -- pure bit ops, EXACT
static __device__ __forceinline__ short8 deq8i(unsigned int q) {
  union { unsigned int u[4]; short8 s8; } r;
#pragma unroll
  for (int j = 0; j < 4; ++j)
    r.u[j] = 0x43004300u | ((q >> (8 * j)) & 0xFu) |
             (((q >> (8 * j + 4)) & 0xFu) << 16);
  return r.s8;
}

#define LOAD_A(SET, CH) do {                                                   \
    _Pragma("unroll")                                                          \
    for (int ks_ = 0; ks_ < 4; ++ks_) {                                        \
      aP[SET][0][ks_] = aB0[(size_t)(((CH) * 4 + ks_)) << 6];                  \
      aP[SET][1][ks_] = aB1[(size_t)(((CH) * 4 + ks_)) << 6];                  \
    }                                                                          \
  } while (0)

#define LOAD_Q(S, CH) do {                                                     \
    _Pragma("unroll")                                                          \
    for (int ks_ = 0; ks_ < 4; ++ks_)                                          \
      qP[S][ks_] = qlane[(size_t)((CH) * 8 + ks_ * 2) * OUT_F];                \
  } while (0)

__global__ __launch_bounds__(256, 2) void gptq_gemm(
    const uint4* __restrict__ xs,           // frag-major x (bf16)
    const int* __restrict__ qweight,        // [512, 11008]
    const float* __restrict__ scales,       // [32, 11008]
    const float* __restrict__ zeros,        // [32, 11008]
    const float* __restrict__ rsum,         // [128, 32]
    float* __restrict__ outp,               // out (atomic) or partials base
    int atomic_mode) {
  const int tid  = threadIdx.x;
  const int lane = tid & 63;
  const int wid  = tid >> 6;
  const int hi   = lane >> 5;
  const int lo32 = lane & 31;

  const int nb = blockIdx.x % NBN;
  const int mb = (blockIdx.x / NBN) & 1;
  const int sl = blockIdx.x / (NBN * 2);

  const int ncol = nb * 128 + wid * 32 + lo32;
  const int m0   = mb * 64;

  float* dst = atomic_mode ? outp : outp + (size_t)sl * MN;

  float sreg[8];
#pragma unroll
  for (int g = 0; g < 8; ++g)
    sreg[g] = scales[(size_t)(sl * 8 + g) * OUT_F + ncol];

  const int* qlane = qweight + (size_t)(sl * (KSLICE / 8) + hi) * OUT_F + ncol;
  const uint4* aB0 = xs + ((size_t)((mb * 2 + 0) * NCHG + sl * KSC) << 8) + lane;
  const uint4* aB1 = xs + ((size_t)((mb * 2 + 1) * NCHG + sl * KSC) << 8) + lane;

  uint4 aP[2][2][4];
  unsigned int qP[3][4];

  LOAD_A(0, 0);                 // A oldest: its wait never couples to same-iter q
  LOAD_Q(0, 0);
  LOAD_Q(1, 1);
  LOAD_Q(2, 2);

  f32x16 acc[2]  = {};
  f32x16 accg[2] = {};

#pragma unroll
  for (int cc = 0; cc < KSC; ++cc) {
    const int p = cc & 1;
    if (cc + 1 < KSC) LOAD_A(p ^ 1, cc + 1);   // A for next iter, issued first

    short8 bF[4];
#pragma unroll
    for (int ks = 0; ks < 4; ++ks)
      bF[ks] = deq8i(qP[cc % 3][ks]);

    if (cc + 3 < KSC) LOAD_Q(cc % 3, cc + 3);  // q issued after A (stays newer)

#pragma unroll
    for (int ks = 0; ks < 4; ++ks) {
      union { uint4 u; short8 s8; } a0, a1;
      a0.u = aP[p][0][ks];
      a1.u = aP[p][1][ks];
      accg[0] = __builtin_amdgcn_mfma_f32_32x32x16_bf16(a0.s8, bF[ks], accg[0], 0, 0, 0);
      accg[1] = __builtin_amdgcn_mfma_f32_32x32x16_bf16(a1.s8, bF[ks], accg[1], 0, 0, 0);
    }

    if (cc & 1) {                               // group boundary (2 chunks)
      const float s = sreg[cc >> 1];
#pragma unroll
      for (int j = 0; j < 16; ++j) {
        acc[0][j] += s * accg[0][j];
        acc[1][j] += s * accg[1][j];
        accg[0][j] = 0.f;
        accg[1][j] = 0.f;
      }
    }
  }

  // epilogue: acc holds sum_g s_g*P_g; subtract sum_g (128 s_g + z_g) rsum_g[row]
  float cg[8];
#pragma unroll
  for (int g = 0; g < 8; ++g)
    cg[g] = 128.f * sreg[g] + zeros[(size_t)(sl * 8 + g) * OUT_F + ncol];

#pragma unroll
  for (int mi = 0; mi < 2; ++mi) {
#pragma unroll
    for (int reg = 0; reg < 16; ++reg) {
      int row = m0 + mi * 32 + 4 * hi + (reg & 3) + 8 * (reg >> 2);
      const float4* rp = (const float4*)(rsum + (size_t)row * NGRP + sl * 8);
      float4 r0 = rp[0], r1 = rp[1];
      float corr = cg[0] * r0.x + cg[1] * r0.y + cg[2] * r0.z + cg[3] * r0.w +
                   cg[4] * r1.x + cg[5] * r1.y + cg[6] * r1.z + cg[7] * r1.w;
      float val = acc[mi][reg] - corr;
      if (atomic_mode) {
        atomicAdd(dst + (size_t)row * OUT_F + ncol, val);
      } else {
        dst[(size_t)row * OUT_F + ncol] = val;
      }
    }
  }
}

extern "C" void kernel_launch(void* const* d_in, const int* in_sizes, int n_in,
                              void* d_out, int out_size, void* d_ws, size_t ws_size,
                              hipStream_t stream) {
  const float* x       = (const float*)d_in[0];
  const int*   qweight = (const int*)d_in[1];
  const float* scales  = (const float*)d_in[2];
  const float* zeros   = (const float*)d_in[3];
  float*       outp    = (float*)d_out;

  const size_t xs_bytes   = (size_t)BATCH * IN_F * sizeof(unsigned short);  // 1 MB
  const size_t rs_bytes   = (size_t)BATCH * NGRP * sizeof(float);           // 16 KB
  const size_t part_bytes = (size_t)SPLIT * MN * sizeof(float);             // 22.5 MB
  int partials = (ws_size >= xs_bytes + rs_bytes + part_bytes) ? 1 : 0;

  uint4* xs   = (uint4*)d_ws;
  float* rsum = (float*)((char*)d_ws + xs_bytes);
  float* part = (float*)((char*)d_ws + xs_bytes + rs_bytes);

  cvt_swz<<<256, 256, 0, stream>>>(x, xs, rsum);

  if (partials) {
    gptq_gemm<<<NBLK, 256, 0, stream>>>(xs, qweight, scales, zeros, rsum, part, 0);
    reduce_kernel<<<688, 256, 0, stream>>>(part, outp);
  } else {
    zero_out<<<344, 256, 0, stream>>>(outp);
    gptq_gemm<<<NBLK, 256, 0, stream>>>(xs, qweight, scales, zeros, rsum, outp, 1);
  }
}

// Round 11
// 48.681 us; speedup vs baseline: 1.5214x; 1.5214x over previous
//
#include <hip/hip_runtime.h>
#include <hip/hip_bf16.h>
#include <stdint.h>

// GPTQ 4-bit fused dequant + GEMM.  x[128,4096]f32 @ W[4096,11008] -> out[128,11008]f32
// W[k][n] = scales[k/128][n] * nibble(qweight[k/8][n], k%8) - zeros[k/128][n]
//
// R11 = R8 (zero-LDS main loop, frag-major A, in-reg deq, 32x32x16 MFMA,
//      WM=64, SPLIT=4) + in-block K-TEAM split for TLP:
//      512-thread blocks = 8 waves = 2 teams; team t does chunks [t*8, t*8+8)
//      of the K-slice; team1 -> 32KB LDS, one __syncthreads, team0 adds+writes.
//      Total waves 2752 -> 5504 (21.5/CU) at CONSTANT total VALU/HBM/VGPR.
//      (R9 got TLP by tile-shrink: 2x VALU -> lost. R10 cut VALU: 128 VGPR,
//      spills -> lost. This is the no-tax TLP move.)

#define IN_F   4096
#define OUT_F  11008
#define BATCH  128
#define SPLIT  4
#define KSLICE (IN_F / SPLIT)   // 1024
#define KSC    (KSLICE / 64)    // 16 chunks per slice
#define KST    (KSC / 2)        // 8 chunks per team
#define NCHG   (IN_F / 64)      // 64 global chunks
#define NBN    86               // n-blocks (128 cols each)
#define NBLK   (NBN * 2 * SPLIT)// 688 blocks (512 threads)
#define MN     (BATCH * OUT_F)  // 1409024

typedef __attribute__((ext_vector_type(8)))  short short8;
typedef __attribute__((ext_vector_type(16))) float f32x16;

static __device__ __forceinline__ unsigned int f2bf_pack(float lo, float hi) {
  // round-to-nearest-even bf16 pair packed into one u32
  unsigned int a = __float_as_uint(lo);
  unsigned int b = __float_as_uint(hi);
  a += 0x7FFFu + ((a >> 16) & 1u);
  b += 0x7FFFu + ((b >> 16) & 1u);
  return (a >> 16) | (b & 0xFFFF0000u);
}

// x[128][4096] f32 -> xs in fragment-major order:
//   16B unit index = ((mt*64 + cg)*4 + ks)*64 + lane,  lane = hi*32 + lo32
//   holding x[mt*32 + lo32][cg*64 + ks*16 + hi*8 + 0..7] as bf16.
__global__ __launch_bounds__(256) void cvt_swz(const float* __restrict__ x,
                                               uint4* __restrict__ xs) {
  int t  = blockIdx.x * 256 + threadIdx.x;   // 65536 threads
  int m  = t >> 9;                           // 0..127
  int k  = (t & 511) * 8;                    // 0..4088, step 8
  float4 u0 = *(const float4*)(x + (size_t)m * IN_F + k);
  float4 u1 = *(const float4*)(x + (size_t)m * IN_F + k + 4);
  uint4 o;
  o.x = f2bf_pack(u0.x, u0.y);
  o.y = f2bf_pack(u0.z, u0.w);
  o.z = f2bf_pack(u1.x, u1.y);
  o.w = f2bf_pack(u1.z, u1.w);
  int mt = m >> 5, lo32 = m & 31;
  int cg = k >> 6, ks = (k >> 4) & 3, hi = (k >> 3) & 1;
  size_t idx = (size_t)(((mt * NCHG + cg) * 4 + ks) << 6) + hi * 32 + lo32;
  xs[idx] = o;
}

__global__ __launch_bounds__(256) void zero_out(float* __restrict__ out) {
  int base = (blockIdx.x * 256 + threadIdx.x) * 16;   // 344 blocks
  float4 z = {0.f, 0.f, 0.f, 0.f};
#pragma unroll
  for (int j = 0; j < 4; ++j) *(float4*)(out + base + j * 4) = z;
}

__global__ __launch_bounds__(256) void reduce_kernel(const float* __restrict__ part,
                                                     float* __restrict__ out) {
  int base = (blockIdx.x * 256 + threadIdx.x) * 8;    // 688 blocks
  float4 s0 = {0.f, 0.f, 0.f, 0.f}, s1 = s0;
#pragma unroll
  for (int s = 0; s < SPLIT; ++s) {
    const float* p = part + (size_t)s * MN + base;
    float4 a = *(const float4*)(p);
    float4 b = *(const float4*)(p + 4);
    s0.x += a.x; s0.y += a.y; s0.z += a.z; s0.w += a.w;
    s1.x += b.x; s1.y += b.y; s1.z += b.z; s1.w += b.w;
  }
  *(float4*)(out + base)     = s0;
  *(float4*)(out + base + 4) = s1;
}

// dequant one packed int32 (8 k-nibbles at one col) into a bf16 B-fragment
static __device__ __forceinline__ short8 deq8(unsigned int q, float s, float z) {
  float f[8];
#pragma unroll
  for (int j = 0; j < 8; ++j)
    f[j] = s * (float)((q >> (4 * j)) & 0xFu) - z;
  union { unsigned int u[4]; short8 s8; } r;
#pragma unroll
  for (int j = 0; j < 4; ++j)
    r.u[j] = f2bf_pack(f[2 * j], f[2 * j + 1]);
  return r.s8;
}

// load 4 q-words (one chunk's B data for this lane) into prefetch set S
#define LOAD_Q(S, CC) do {                                                     \
    _Pragma("unroll")                                                          \
    for (int ks_ = 0; ks_ < 4; ++ks_)                                          \
      qP[S][ks_] = qlane[(size_t)((CC) * 8 + ks_ * 2) * OUT_F];                \
  } while (0)

__global__ __launch_bounds__(512) void gptq_gemm(
    const uint4* __restrict__ xs,           // frag-major x (bf16)
    const int* __restrict__ qweight,        // [512, 11008]
    const float* __restrict__ scales,       // [32, 11008]
    const float* __restrict__ zeros,        // [32, 11008]
    float* __restrict__ outp,               // out (atomic) or partials base
    int atomic_mode) {
  __shared__ float red[4][2][16][64];       // 32 KB team-reduce buffer

  const int tid    = threadIdx.x;
  const int lane   = tid & 63;
  const int wid    = tid >> 6;              // 0..7
  const int team   = wid >> 2;              // 0/1: K-half
  const int wlocal = wid & 3;               // 0..3: n-quarter
  const int hi     = lane >> 5;             // 0/1: k-half within fragment
  const int lo32   = lane & 31;

  const int nb = blockIdx.x % NBN;
  const int mb = (blockIdx.x / NBN) & 1;
  const int sl = blockIdx.x / (NBN * 2);

  const int ncol = nb * 128 + wlocal * 32 + lo32;  // this lane's output column
  const int m0   = mb * 64;                        // rows m0..m0+63

  float* dst = atomic_mode ? outp : outp + (size_t)sl * MN;

  // per-lane scale/zero for this team's 4 groups (group = 128 k = 2 chunks)
  float sreg[4], zreg[4];
#pragma unroll
  for (int g = 0; g < 4; ++g) {
    sreg[g] = scales[(size_t)(sl * 8 + team * 4 + g) * OUT_F + ncol];
    zreg[g] = zeros [(size_t)(sl * 8 + team * 4 + g) * OUT_F + ncol];
  }

  // base pointers (team offset: 8 chunks = 512 k = 64 q-rows)
  const int* qlane = qweight + (size_t)(sl * (KSLICE / 8) + team * 64 + hi) * OUT_F + ncol;
  const uint4* aB0 = xs + ((size_t)((mb * 2 + 0) * NCHG + sl * KSC + team * KST) << 8) + lane;
  const uint4* aB1 = xs + ((size_t)((mb * 2 + 1) * NCHG + sl * KSC + team * KST) << 8) + lane;

  unsigned int qP[3][4];
  LOAD_Q(0, 0);
  LOAD_Q(1, 1);
  LOAD_Q(2, 2);

  f32x16 acc[2] = {};

#pragma unroll
  for (int cc = 0; cc < KST; ++cc) {
    // A fragments: coalesced (base + lane*16B), xs is L2-resident
    uint4 aF[2][4];
#pragma unroll
    for (int ks = 0; ks < 4; ++ks) {
      aF[0][ks] = aB0[(size_t)(cc * 4 + ks) << 6];
      aF[1][ks] = aB1[(size_t)(cc * 4 + ks) << 6];
    }

    // dequant chunk cc's q-words (covers A-load latency with VALU)
    const float s = sreg[cc >> 1], z = zreg[cc >> 1];
    short8 bF[4];
#pragma unroll
    for (int ks = 0; ks < 4; ++ks)
      bF[ks] = deq8(qP[cc % 3][ks], s, z);

    // prefetch chunk cc+3's q-words into the just-freed set
    if (cc + 3 < KST) LOAD_Q(cc % 3, cc + 3);

    // 8 MFMAs (k = 4 x 16)
#pragma unroll
    for (int ks = 0; ks < 4; ++ks) {
      union { uint4 u; short8 s8; } a0, a1;
      a0.u = aF[0][ks];
      a1.u = aF[1][ks];
      acc[0] = __builtin_amdgcn_mfma_f32_32x32x16_bf16(a0.s8, bF[ks], acc[0], 0, 0, 0);
      acc[1] = __builtin_amdgcn_mfma_f32_32x32x16_bf16(a1.s8, bF[ks], acc[1], 0, 0, 0);
    }
  }

  // ---- team reduce: team1 -> LDS, team0 adds and writes ----
  if (team == 1) {
#pragma unroll
    for (int mi = 0; mi < 2; ++mi)
#pragma unroll
      for (int reg = 0; reg < 16; ++reg)
        red[wlocal][mi][reg][lane] = acc[mi][reg];
  }
  __syncthreads();

  if (team == 0) {
    // epilogue: C/D layout col=lane&31, row=(reg&3)+8*(reg>>2)+4*(lane>>5)
#pragma unroll
    for (int mi = 0; mi < 2; ++mi) {
#pragma unroll
      for (int reg = 0; reg < 16; ++reg) {
        float val = acc[mi][reg] + red[wlocal][mi][reg][lane];
        int row = m0 + mi * 32 + 4 * hi + (reg & 3) + 8 * (reg >> 2);
        if (atomic_mode) {
          atomicAdd(dst + (size_t)row * OUT_F + ncol, val);
        } else {
          dst[(size_t)row * OUT_F + ncol] = val;
        }
      }
    }
  }
}

extern "C" void kernel_launch(void* const* d_in, const int* in_sizes, int n_in,
                              void* d_out, int out_size, void* d_ws, size_t ws_size,
                              hipStream_t stream) {
  const float* x       = (const float*)d_in[0];
  const int*   qweight = (const int*)d_in[1];
  const float* scales  = (const float*)d_in[2];
  const float* zeros   = (const float*)d_in[3];
  float*       outp    = (float*)d_out;

  const size_t xs_bytes   = (size_t)BATCH * IN_F * sizeof(unsigned short);  // 1 MB
  const size_t part_bytes = (size_t)SPLIT * MN * sizeof(float);             // 22.5 MB
  int partials = (ws_size >= xs_bytes + part_bytes) ? 1 : 0;

  uint4* xs   = (uint4*)d_ws;
  float* part = (float*)((char*)d_ws + xs_bytes);

  // x f32 -> frag-major bf16 (1 MB): 128*4096 elems, 8/thread -> 256 blocks
  cvt_swz<<<256, 256, 0, stream>>>(x, xs);

  if (partials) {
    gptq_gemm<<<NBLK, 512, 0, stream>>>(xs, qweight, scales, zeros, part, 0);
    reduce_kernel<<<688, 256, 0, stream>>>(part, outp);
  } else {
    zero_out<<<344, 256, 0, stream>>>(outp);
    gptq_gemm<<<NBLK, 512, 0, stream>>>(xs, qweight, scales, zeros, outp, 1);
  }
}

// Round 12
// 42.371 us; speedup vs baseline: 1.7479x; 1.1489x over previous
//
#include <hip/hip_runtime.h>
#include <hip/hip_bf16.h>
#include <stdint.h>

// GPTQ 4-bit fused dequant + GEMM.  x[128,4096]f32 @ W[4096,11008] -> out[128,11008]f32
// W[k][n] = scales[k/128][n] * nibble(qweight[k/8][n], k%8) - zeros[k/128][n]
//
// R12 = R8 geometry (zero-LDS, frag-major A, WM=64, MB=2, SPLIT=4, 688x256,
//       q-prefetch 3-deep) + cheap dequant done RIGHT:
//   - bf16(0x4300|q) = 128+q EXACT -> dequant is 4 bit-ops per u32 (deq8i).
//   - SINGLE accumulator + running rescale: MFMA accumulates raw P = sum x*(128+q)
//     into acc; at group boundary acc *= s_g/s_{g+1} (16 muls); epilogue applies
//     s_last and subtracts sum_g (128 s_g + z_g) * rsum_g[row]  (rsum from cvt,
//     verified in R10). Telescoping gives each P_g coefficient s_g exactly.
//   R10 failed on +64 VGPR (dual acc) -> spills; this has ~+15 VGPR only.

#define IN_F   4096
#define OUT_F  11008
#define BATCH  128
#define SPLIT  4
#define KSLICE (IN_F / SPLIT)   // 1024
#define KSC    (KSLICE / 64)    // 16 chunks per slice
#define NCHG   (IN_F / 64)      // 64 global chunks
#define NBN    86               // n-blocks (128 cols each)
#define NBLK   (NBN * 2 * SPLIT)// 688
#define MN     (BATCH * OUT_F)  // 1409024
#define NGRP   (IN_F / 128)     // 32 groups

typedef __attribute__((ext_vector_type(8)))  short short8;
typedef __attribute__((ext_vector_type(16))) float f32x16;

static __device__ __forceinline__ unsigned int f2bf_pack(float lo, float hi) {
  unsigned int a = __float_as_uint(lo);
  unsigned int b = __float_as_uint(hi);
  a += 0x7FFFu + ((a >> 16) & 1u);
  b += 0x7FFFu + ((b >> 16) & 1u);
  return (a >> 16) | (b & 0xFFFF0000u);
}

static __device__ __forceinline__ float bf16_round_f32(float v) {
  unsigned int u = __float_as_uint(v);
  u += 0x7FFFu + ((u >> 16) & 1u);
  return __uint_as_float(u & 0xFFFF0000u);
}

// x[128][4096] f32 -> xs frag-major bf16 (16B unit = ((mt*64+cg)*4+ks)*64+lane,
// lane = hi*32+lo32, holding x[mt*32+lo32][cg*64+ks*16+hi*8 + 0..7])
// + rsum[128][32]: per-(row, group) sum of the bf16-ROUNDED x values.
__global__ __launch_bounds__(256) void cvt_swz(const float* __restrict__ x,
                                               uint4* __restrict__ xs,
                                               float* __restrict__ rsum) {
  int t  = blockIdx.x * 256 + threadIdx.x;   // 65536 threads
  int m  = t >> 9;                           // 0..127
  int k  = (t & 511) * 8;                    // 0..4088, step 8
  float4 u0 = *(const float4*)(x + (size_t)m * IN_F + k);
  float4 u1 = *(const float4*)(x + (size_t)m * IN_F + k + 4);
  uint4 o;
  o.x = f2bf_pack(u0.x, u0.y);
  o.y = f2bf_pack(u0.z, u0.w);
  o.z = f2bf_pack(u1.x, u1.y);
  o.w = f2bf_pack(u1.z, u1.w);
  int mt = m >> 5, lo32 = m & 31;
  int cg = k >> 6, ks = (k >> 4) & 3, hi = (k >> 3) & 1;
  size_t idx = (size_t)(((mt * NCHG + cg) * 4 + ks) << 6) + hi * 32 + lo32;
  xs[idx] = o;

  float s8 = bf16_round_f32(u0.x) + bf16_round_f32(u0.y) +
             bf16_round_f32(u0.z) + bf16_round_f32(u0.w) +
             bf16_round_f32(u1.x) + bf16_round_f32(u1.y) +
             bf16_round_f32(u1.z) + bf16_round_f32(u1.w);
  s8 += __shfl_xor(s8, 1, 16);
  s8 += __shfl_xor(s8, 2, 16);
  s8 += __shfl_xor(s8, 4, 16);
  s8 += __shfl_xor(s8, 8, 16);
  if ((t & 15) == 0) {
    int g = (t & 511) >> 4;                  // 0..31
    rsum[m * NGRP + g] = s8;
  }
}

__global__ __launch_bounds__(256) void zero_out(float* __restrict__ out) {
  int base = (blockIdx.x * 256 + threadIdx.x) * 16;   // 344 blocks
  float4 z = {0.f, 0.f, 0.f, 0.f};
#pragma unroll
  for (int j = 0; j < 4; ++j) *(float4*)(out + base + j * 4) = z;
}

__global__ __launch_bounds__(256) void reduce_kernel(const float* __restrict__ part,
                                                     float* __restrict__ out) {
  int base = (blockIdx.x * 256 + threadIdx.x) * 8;    // 688 blocks
  float4 s0 = {0.f, 0.f, 0.f, 0.f}, s1 = s0;
#pragma unroll
  for (int s = 0; s < SPLIT; ++s) {
    const float* p = part + (size_t)s * MN + base;
    float4 a = *(const float4*)(p);
    float4 b = *(const float4*)(p + 4);
    s0.x += a.x; s0.y += a.y; s0.z += a.z; s0.w += a.w;
    s1.x += b.x; s1.y += b.y; s1.z += b.z; s1.w += b.w;
  }
  *(float4*)(out + base)     = s0;
  *(float4*)(out + base + 4) = s1;
}

// dequant one packed int32 into bf16 (128 + q) -- pure bit ops, EXACT
static __device__ __forceinline__ short8 deq8i(unsigned int q) {
  union { unsigned int u[4]; short8 s8; } r;
#pragma unroll
  for (int j = 0; j < 4; ++j)
    r.u[j] = 0x43004300u | ((q >> (8 * j)) & 0xFu) |
             (((q >> (8 * j + 4)) & 0xFu) << 16);
  return r.s8;
}

// load 4 q-words (one chunk's B data for this lane) into prefetch set S
#define LOAD_Q(S, CC) do {                                                     \
    _Pragma("unroll")                                                          \
    for (int ks_ = 0; ks_ < 4; ++ks_)                                          \
      qP[S][ks_] = qlane[(size_t)((CC) * 8 + ks_ * 2) * OUT_F];                \
  } while (0)

__global__ __launch_bounds__(256) void gptq_gemm(
    const uint4* __restrict__ xs,           // frag-major x (bf16)
    const int* __restrict__ qweight,        // [512, 11008]
    const float* __restrict__ scales,       // [32, 11008]
    const float* __restrict__ zeros,        // [32, 11008]
    const float* __restrict__ rsum,         // [128, 32]
    float* __restrict__ outp,               // out (atomic) or partials base
    int atomic_mode) {
  const int tid  = threadIdx.x;
  const int lane = tid & 63;
  const int wid  = tid >> 6;
  const int hi   = lane >> 5;          // 0/1: k-half within fragment
  const int lo32 = lane & 31;

  const int nb = blockIdx.x % NBN;
  const int mb = (blockIdx.x / NBN) & 1;
  const int sl = blockIdx.x / (NBN * 2);

  const int ncol = nb * 128 + wid * 32 + lo32;  // this lane's output column
  const int m0   = mb * 64;                     // rows m0..m0+63

  float* dst = atomic_mode ? outp : outp + (size_t)sl * MN;

  // scales for this slice's 8 groups; ratios for the running rescale
  float sv[8];
#pragma unroll
  for (int g = 0; g < 8; ++g)
    sv[g] = scales[(size_t)(sl * 8 + g) * OUT_F + ncol];
  float rr[7];
#pragma unroll
  for (int g = 0; g < 7; ++g)
    rr[g] = sv[g] / sv[g + 1];

  const int* qlane = qweight + (size_t)(sl * (KSLICE / 8) + hi) * OUT_F + ncol;
  const uint4* aB0 = xs + ((size_t)((mb * 2 + 0) * NCHG + sl * KSC) << 8) + lane;
  const uint4* aB1 = xs + ((size_t)((mb * 2 + 1) * NCHG + sl * KSC) << 8) + lane;

  unsigned int qP[3][4];
  LOAD_Q(0, 0);
  LOAD_Q(1, 1);
  LOAD_Q(2, 2);

  f32x16 acc[2] = {};

#pragma unroll
  for (int cc = 0; cc < KSC; ++cc) {
    // A fragments: coalesced (base + lane*16B), L1-shared across the 4 waves
    uint4 aF[2][4];
#pragma unroll
    for (int ks = 0; ks < 4; ++ks) {
      aF[0][ks] = aB0[(size_t)(cc * 4 + ks) << 6];
      aF[1][ks] = aB1[(size_t)(cc * 4 + ks) << 6];
    }

    // dequant: pure bit-ops (128+q exact in bf16)
    short8 bF[4];
#pragma unroll
    for (int ks = 0; ks < 4; ++ks)
      bF[ks] = deq8i(qP[cc % 3][ks]);

    if (cc + 3 < KSC) LOAD_Q(cc % 3, cc + 3);

#pragma unroll
    for (int ks = 0; ks < 4; ++ks) {
      union { uint4 u; short8 s8; } a0, a1;
      a0.u = aF[0][ks];
      a1.u = aF[1][ks];
      acc[0] = __builtin_amdgcn_mfma_f32_32x32x16_bf16(a0.s8, bF[ks], acc[0], 0, 0, 0);
      acc[1] = __builtin_amdgcn_mfma_f32_32x32x16_bf16(a1.s8, bF[ks], acc[1], 0, 0, 0);
    }

    // group boundary (group = 2 chunks): acc *= s_g / s_{g+1}
    if ((cc & 1) && cc != KSC - 1) {
      const float r = rr[cc >> 1];
#pragma unroll
      for (int j = 0; j < 16; ++j) {
        acc[0][j] *= r;
        acc[1][j] *= r;
      }
    }
  }

  // epilogue: val = s_last * acc - sum_g (128 s_g + z_g) rsum_g[row]
  float cg[8];
#pragma unroll
  for (int g = 0; g < 8; ++g)
    cg[g] = 128.f * sv[g] + zeros[(size_t)(sl * 8 + g) * OUT_F + ncol];
  const float slast = sv[7];

#pragma unroll
  for (int mi = 0; mi < 2; ++mi) {
#pragma unroll
    for (int reg = 0; reg < 16; ++reg) {
      int row = m0 + mi * 32 + 4 * hi + (reg & 3) + 8 * (reg >> 2);
      const float4* rp = (const float4*)(rsum + (size_t)row * NGRP + sl * 8);
      float4 r0 = rp[0], r1 = rp[1];
      float corr = cg[0] * r0.x + cg[1] * r0.y + cg[2] * r0.z + cg[3] * r0.w +
                   cg[4] * r1.x + cg[5] * r1.y + cg[6] * r1.z + cg[7] * r1.w;
      float val = slast * acc[mi][reg] - corr;
      if (atomic_mode) {
        atomicAdd(dst + (size_t)row * OUT_F + ncol, val);
      } else {
        dst[(size_t)row * OUT_F + ncol] = val;
      }
    }
  }
}

extern "C" void kernel_launch(void* const* d_in, const int* in_sizes, int n_in,
                              void* d_out, int out_size, void* d_ws, size_t ws_size,
                              hipStream_t stream) {
  const float* x       = (const float*)d_in[0];
  const int*   qweight = (const int*)d_in[1];
  const float* scales  = (const float*)d_in[2];
  const float* zeros   = (const float*)d_in[3];
  float*       outp    = (float*)d_out;

  const size_t xs_bytes   = (size_t)BATCH * IN_F * sizeof(unsigned short);  // 1 MB
  const size_t rs_bytes   = (size_t)BATCH * NGRP * sizeof(float);           // 16 KB
  const size_t part_bytes = (size_t)SPLIT * MN * sizeof(float);             // 22.5 MB
  int partials = (ws_size >= xs_bytes + rs_bytes + part_bytes) ? 1 : 0;

  uint4* xs   = (uint4*)d_ws;
  float* rsum = (float*)((char*)d_ws + xs_bytes);
  float* part = (float*)((char*)d_ws + xs_bytes + rs_bytes);

  cvt_swz<<<256, 256, 0, stream>>>(x, xs, rsum);

  if (partials) {
    gptq_gemm<<<NBLK, 256, 0, stream>>>(xs, qweight, scales, zeros, rsum, part, 0);
    reduce_kernel<<<688, 256, 0, stream>>>(part, outp);
  } else {
    zero_out<<<344, 256, 0, stream>>>(outp);
    gptq_gemm<<<NBLK, 256, 0, stream>>>(xs, qweight, scales, zeros, rsum, outp, 1);
  }
}